// Round 9
// baseline (2074.984 us; speedup 1.0000x reference)
//
#include <hip/hip_runtime.h>
#include <hip/hip_bf16.h>

#define NSEQ 512
#define WD   256
#define LD   256
#define NG   1024      // 4*LD gates
#define FEAT 512
#define HID  512
#define NREL 100

typedef _Float16 h2_t __attribute__((ext_vector_type(2)));
typedef _Float16 half8 __attribute__((ext_vector_type(8)));
typedef float f32x4 __attribute__((ext_vector_type(4)));

__device__ __forceinline__ float fsig(float x) {
    x = fminf(fmaxf(x, -30.f), 30.f);
    return 1.f / (1.f + __expf(-x));
}
__device__ __forceinline__ float ftanh(float x) {
    x = fminf(fmaxf(x, -15.f), 15.f);
    float e = __expf(2.f * x);
    return (e - 1.f) / (e + 1.f);
}

__device__ __forceinline__ float fdot2_acc(unsigned a, unsigned b, float c) {
#if __has_builtin(__builtin_amdgcn_fdot2)
    return __builtin_amdgcn_fdot2(__builtin_bit_cast(h2_t, a),
                                  __builtin_bit_cast(h2_t, b), c, false);
#else
    h2_t ha = __builtin_bit_cast(h2_t, a), hb = __builtin_bit_cast(h2_t, b);
    c = fmaf((float)ha.x, (float)hb.x, c);
    return fmaf((float)ha.y, (float)hb.y, c);
#endif
}
__device__ __forceinline__ unsigned pk16(float a, float b) {
    return __builtin_bit_cast(unsigned, __builtin_amdgcn_cvt_pkrtz(a, b));
}

// ---------------- embedding gather ----------------
__global__ void embed_kernel(const int* __restrict__ tok, const float* __restrict__ E,
                             float* __restrict__ x) {
    int b = blockIdx.x;
    int t = tok[b];
    x[b * WD + threadIdx.x] = E[(long long)t * WD + threadIdx.x];
}

// ---------------- routW -> f16 [n][k] (transposed, zero-padded to 112) ----------
__global__ void cvt_routw_kernel(const float* __restrict__ routW, _Float16* __restrict__ rw16) {
    int k = blockIdx.x;       // 512
    int n = threadIdx.x;      // 128 (guard)
    if (n < 112)
        rw16[n * 512 + k] = (n < NREL) ? (_Float16)routW[k * NREL + n] : (_Float16)0.f;
}

// ---------------- MFMA GEMM: C = A(MxK) @ W(KxN) + bias, f16 compute ----------------
__global__ __launch_bounds__(256) void gemm_mfma_kernel(
        const float* __restrict__ A, const float* __restrict__ W,
        const float* __restrict__ bias, float* __restrict__ C,
        int M, int K, int N) {
    __shared__ _Float16 Ah[64][40];   // stride 80B (5x16B): b128-aligned rows
    __shared__ _Float16 Wt[64][40];
    int tid = threadIdx.x, wid = tid >> 6, l = tid & 63;
    int m0 = blockIdx.y * 64, n0 = blockIdx.x * 64;
    f32x4 acc[4] = {};
    int ar = tid >> 2, akq = (tid & 3) * 8;
    int wn = tid & 63, wkp0 = (tid >> 6) * 2;
    for (int k0 = 0; k0 < K; k0 += 32) {
        float4 a0 = *(const float4*)&A[(m0 + ar) * K + k0 + akq];
        float4 a1 = *(const float4*)&A[(m0 + ar) * K + k0 + akq + 4];
        uint4 ap = { pk16(a0.x, a0.y), pk16(a0.z, a0.w),
                     pk16(a1.x, a1.y), pk16(a1.z, a1.w) };
        *(uint4*)&Ah[ar][akq] = ap;
        #pragma unroll
        for (int it = 0; it < 4; ++it) {
            int kp = wkp0 + it * 8;
            float w0 = W[(k0 + kp) * N + n0 + wn];
            float w1 = W[(k0 + kp + 1) * N + n0 + wn];
            ((unsigned*)&Wt[wn][0])[kp >> 1] = pk16(w0, w1);
        }
        __syncthreads();
        half8 af = *(const half8*)&Ah[wid * 16 + (l & 15)][(l >> 4) * 8];
        #pragma unroll
        for (int nt = 0; nt < 4; ++nt) {
            half8 bf = *(const half8*)&Wt[nt * 16 + (l & 15)][(l >> 4) * 8];
            acc[nt] = __builtin_amdgcn_mfma_f32_16x16x32_f16(af, bf, acc[nt], 0, 0, 0);
        }
        __syncthreads();
    }
    int rbase = m0 + wid * 16 + (l >> 4) * 4;
    #pragma unroll
    for (int nt = 0; nt < 4; ++nt) {
        int col = n0 + nt * 16 + (l & 15);
        float b = bias ? bias[col] : 0.f;
        #pragma unroll
        for (int reg = 0; reg < 4; ++reg)
            C[(rbase + reg) * N + col] = acc[nt][reg] + b;
    }
}

// ---------------- bidirectional LSTM layer: merged fwd+bwd ----------------
// 4 blocks x 512 threads; block owns 64 fwd units AND 64 bwd units.
// Per iteration (4 phases): dot_fwd -> [act_fwd || poll_bwd] -> dot_bwd ->
// [act_bwd || poll_fwd]. Each direction's IC store gets a full opposite-
// direction compute phase of hiding before its poll. Protocol: round-3
// proven (u64 tag|value, parity slots, relaxed agent-scope IC ops);
// distance-2 overwrite proof holds under the 4-phase schedule.
__global__ __launch_bounds__(512, 2) void lstm_kernel(
        const float* __restrict__ Xf, const float* __restrict__ Xb,
        const float* __restrict__ WhF, const float* __restrict__ WhB,
        float* __restrict__ H, unsigned long long* __restrict__ stage) {
    int tid = threadIdx.x;
    int blk = blockIdx.x;                  // 0..3
    unsigned long long* stgF = stage;      // [2 slots][256] u64
    unsigned long long* stgB = stage + 512;
    int cl  = tid & 255;
    int ksl = tid >> 8;                    // k-slice 0..1 (128 k each)
    int col = (cl >> 6) * 256 + blk * 64 + (cl & 63);
    int lane = tid & 63;

    // 2 x 128 f16 weights, fully unrolled static indexing (no scratch)
    unsigned w2f[64], w2b[64];
    #pragma unroll
    for (int m = 0; m < 64; ++m)
        w2f[m] = pk16(WhF[(ksl * 128 + 2 * m) * NG + col],
                      WhF[(ksl * 128 + 2 * m + 1) * NG + col]);
    #pragma unroll
    for (int m = 0; m < 64; ++m)
        w2b[m] = pk16(WhB[(ksl * 128 + 2 * m) * NG + col],
                      WhB[(ksl * 128 + 2 * m + 1) * NG + col]);

    alignas(16) __shared__ unsigned hpkF[128];   // 256 h as f16 pairs
    alignas(16) __shared__ unsigned hpkB[128];
    __shared__ float partialF[2][256];
    __shared__ float partialB[2][256];
    if (tid < 128) { hpkF[tid] = 0u; hpkB[tid] = 0u; }
    float c_regF = 0.f, c_regB = 0.f;
    __syncthreads();

    _Float16* hpF16 = (_Float16*)hpkF;
    _Float16* hpB16 = (_Float16*)hpkB;
    int pidx = tid & 255;
    bool pollRemote = (tid >= 256) && ((pidx >> 6) != blk);

    for (int s = 0; s < NSEQ; ++s) {
        int tF = s, tB = NSEQ - 1 - s;
        float xgF[4], xgB[4];
        if (tid < 64) {
            #pragma unroll
            for (int g = 0; g < 4; ++g) {
                xgF[g] = Xf[tF * NG + g * 256 + blk * 64 + lane];
                xgB[g] = Xb[tB * NG + g * 256 + blk * 64 + lane];
            }
        }
        // ---- phase 1: dot fwd (h_f(s-1) in hpkF) ----
        {
            const uint4* hp4 = (const uint4*)&hpkF[ksl * 64];
            float a0 = 0.f, a1 = 0.f;
            #pragma unroll
            for (int m = 0; m < 16; ++m) {
                uint4 hp = hp4[m];
                a0 = fdot2_acc(w2f[m * 4 + 0], hp.x, a0);
                a1 = fdot2_acc(w2f[m * 4 + 1], hp.y, a1);
                a0 = fdot2_acc(w2f[m * 4 + 2], hp.z, a0);
                a1 = fdot2_acc(w2f[m * 4 + 3], hp.w, a1);
            }
            partialF[ksl][cl] = a0 + a1;
        }
        __syncthreads();
        // ---- phase 2: fwd act (wave0) || poll bwd h(s-1) (pollers) ----
        if (tid < 64) {
            float z[4];
            #pragma unroll
            for (int g = 0; g < 4; ++g)
                z[g] = xgF[g] + partialF[0][g * 64 + lane] + partialF[1][g * 64 + lane];
            c_regF = fsig(z[1]) * c_regF + fsig(z[0]) * ftanh(z[2]);
            float h = fsig(z[3]) * ftanh(c_regF);
            unsigned long long pk = ((unsigned long long)(unsigned)(s + 1) << 32)
                                  | (unsigned long long)__float_as_uint(h);
            __hip_atomic_store(&stgF[(s & 1) * 256 + blk * 64 + lane], pk,
                               __ATOMIC_RELAXED, __HIP_MEMORY_SCOPE_AGENT);
            hpF16[blk * 64 + lane] = (_Float16)h;
            H[tF * FEAT + blk * 64 + lane] = h;
        } else if (pollRemote && s > 0) {
            const unsigned long long* src = &stgB[((s - 1) & 1) * 256 + pidx];
            unsigned long long pk;
            do {
                pk = __hip_atomic_load((unsigned long long*)src,
                                       __ATOMIC_RELAXED, __HIP_MEMORY_SCOPE_AGENT);
            } while ((unsigned)(pk >> 32) != (unsigned)s);
            hpB16[pidx] = (_Float16)__uint_as_float((unsigned)(pk & 0xffffffffu));
        }
        __syncthreads();
        // ---- phase 3: dot bwd (h_b(s-1) in hpkB) ----
        {
            const uint4* hp4 = (const uint4*)&hpkB[ksl * 64];
            float a0 = 0.f, a1 = 0.f;
            #pragma unroll
            for (int m = 0; m < 16; ++m) {
                uint4 hp = hp4[m];
                a0 = fdot2_acc(w2b[m * 4 + 0], hp.x, a0);
                a1 = fdot2_acc(w2b[m * 4 + 1], hp.y, a1);
                a0 = fdot2_acc(w2b[m * 4 + 2], hp.z, a0);
                a1 = fdot2_acc(w2b[m * 4 + 3], hp.w, a1);
            }
            partialB[ksl][cl] = a0 + a1;
        }
        __syncthreads();
        // ---- phase 4: bwd act (wave0) || poll fwd h(s) (pollers) ----
        if (tid < 64) {
            float z[4];
            #pragma unroll
            for (int g = 0; g < 4; ++g)
                z[g] = xgB[g] + partialB[0][g * 64 + lane] + partialB[1][g * 64 + lane];
            c_regB = fsig(z[1]) * c_regB + fsig(z[0]) * ftanh(z[2]);
            float h = fsig(z[3]) * ftanh(c_regB);
            unsigned long long pk = ((unsigned long long)(unsigned)(s + 1) << 32)
                                  | (unsigned long long)__float_as_uint(h);
            __hip_atomic_store(&stgB[(s & 1) * 256 + blk * 64 + lane], pk,
                               __ATOMIC_RELAXED, __HIP_MEMORY_SCOPE_AGENT);
            hpB16[blk * 64 + lane] = (_Float16)h;
            H[tB * FEAT + LD + blk * 64 + lane] = h;
        } else if (pollRemote && s + 1 < NSEQ) {
            const unsigned long long* src = &stgF[(s & 1) * 256 + pidx];
            unsigned long long pk;
            do {
                pk = __hip_atomic_load((unsigned long long*)src,
                                       __ATOMIC_RELAXED, __HIP_MEMORY_SCOPE_AGENT);
            } while ((unsigned)(pk >> 32) != (unsigned)(s + 1));
            hpF16[pidx] = (_Float16)__uint_as_float((unsigned)(pk & 0xffffffffu));
        }
        __syncthreads();
    }
}

// ---------------- arc scorer (unchanged) ----------------
__global__ __launch_bounds__(256) void arc_kernel(
        const float* __restrict__ Hh, const float* __restrict__ Mh,
        const float* __restrict__ outW, const float* __restrict__ outB,
        float* __restrict__ out) {
    __shared__ float Hs[16][513];
    __shared__ float Ms[16][513];
    __shared__ float wW[512];
    int tid = threadIdx.x;
    int i0 = blockIdx.y * 16, j0 = blockIdx.x * 16;
    int r = tid >> 4, kb = (tid & 15) * 4;
    #pragma unroll
    for (int q = 0; q < 8; ++q) {
        int k = kb + q * 64;
        float4 hv = *(const float4*)&Hh[(i0 + r) * HID + k];
        Hs[r][k] = hv.x; Hs[r][k + 1] = hv.y; Hs[r][k + 2] = hv.z; Hs[r][k + 3] = hv.w;
        float4 mv = *(const float4*)&Mh[(j0 + r) * HID + k];
        Ms[r][k] = mv.x; Ms[r][k + 1] = mv.y; Ms[r][k + 2] = mv.z; Ms[r][k + 3] = mv.w;
    }
    wW[tid] = outW[tid];
    wW[tid + 256] = outW[tid + 256];
    __syncthreads();
    int ti = tid >> 4, tj = tid & 15;
    float acc = 0.f;
    #pragma unroll 4
    for (int k = 0; k < 512; ++k)
        acc += ftanh(Hs[ti][k] + Ms[tj][k]) * wW[k];
    out[(i0 + ti) * NSEQ + (j0 + tj)] = acc + outB[0];
}

// ---------------- relation scorer: MFMA f16 (R8-fixed staging) ----------------
__global__ __launch_bounds__(256) void rel_mfma_kernel(
        const float* __restrict__ Rh, const float* __restrict__ Rm,
        const _Float16* __restrict__ rw16, const float* __restrict__ routB,
        float* __restrict__ out) {
    __shared__ _Float16 act[64][72];    // stride 144B (9x16B)
    __shared__ _Float16 rw[112][72];
    __shared__ float rh_s[512];
    int tid = threadIdx.x, wid = tid >> 6, l = tid & 63;
    int i = blockIdx.x >> 3;
    int j0 = (blockIdx.x & 7) * 64;
    if (tid < 128)
        *(float4*)&rh_s[tid * 4] = *(const float4*)&Rh[i * HID + tid * 4];
    f32x4 acc[7] = {};
    int aj = tid >> 2, aks = (tid & 3) * 16;
    __syncthreads();

    for (int c = 0; c < 8; ++c) {
        int k0 = c * 64;
        #pragma unroll
        for (int rep = 0; rep < 14; ++rep) {
            int idx = rep * 256 + tid;
            int n = idx >> 5, ku = idx & 31;
            ((unsigned*)&rw[n][0])[ku] = *(const unsigned*)&rw16[n * 512 + k0 + ku * 2];
        }
        {
            const float* rmp = &Rm[(j0 + aj) * HID + k0 + aks];
            float4 r0 = *(const float4*)&rmp[0];
            float4 r1 = *(const float4*)&rmp[4];
            float4 r2 = *(const float4*)&rmp[8];
            float4 r3 = *(const float4*)&rmp[12];
            const float* rh = &rh_s[k0 + aks];
            float t0 = ftanh(rh[0]  + r0.x), t1 = ftanh(rh[1]  + r0.y);
            float t2 = ftanh(rh[2]  + r0.z), t3 = ftanh(rh[3]  + r0.w);
            float t4 = ftanh(rh[4]  + r1.x), t5 = ftanh(rh[5]  + r1.y);
            float t6 = ftanh(rh[6]  + r1.z), t7 = ftanh(rh[7]  + r1.w);
            uint4 p0 = { pk16(t0, t1), pk16(t2, t3), pk16(t4, t5), pk16(t6, t7) };
            *(uint4*)&act[aj][aks] = p0;
            float u0 = ftanh(rh[8]  + r2.x), u1 = ftanh(rh[9]  + r2.y);
            float u2 = ftanh(rh[10] + r2.z), u3 = ftanh(rh[11] + r2.w);
            float u4 = ftanh(rh[12] + r3.x), u5 = ftanh(rh[13] + r3.y);
            float u6 = ftanh(rh[14] + r3.z), u7 = ftanh(rh[15] + r3.w);
            uint4 p1 = { pk16(u0, u1), pk16(u2, u3), pk16(u4, u5), pk16(u6, u7) };
            *(uint4*)&act[aj][aks + 8] = p1;
        }
        __syncthreads();
        #pragma unroll
        for (int kk = 0; kk < 2; ++kk) {
            half8 af = *(const half8*)&act[wid * 16 + (l & 15)][kk * 32 + (l >> 4) * 8];
            #pragma unroll
            for (int nt = 0; nt < 7; ++nt) {
                half8 bf = *(const half8*)&rw[nt * 16 + (l & 15)][kk * 32 + (l >> 4) * 8];
                acc[nt] = __builtin_amdgcn_mfma_f32_16x16x32_f16(af, bf, acc[nt], 0, 0, 0);
            }
        }
        __syncthreads();
    }
    int jbase = j0 + wid * 16 + (l >> 4) * 4;
    #pragma unroll
    for (int nt = 0; nt < 7; ++nt) {
        int col = nt * 16 + (l & 15);
        if (col < NREL) {
            float b = routB[col];
            #pragma unroll
            for (int reg = 0; reg < 4; ++reg)
                out[(long long)(i * NSEQ + jbase + reg) * NREL + col] = acc[nt][reg] + b;
        }
    }
}

extern "C" void kernel_launch(void* const* d_in, const int* in_sizes, int n_in,
                              void* d_out, int out_size, void* d_ws, size_t ws_size,
                              hipStream_t stream) {
    const int*   tokens = (const int*)d_in[0];
    const float* E      = (const float*)d_in[1];
    const float* Wx_f1  = (const float*)d_in[2];
    const float* Wh_f1  = (const float*)d_in[3];
    const float* b_f1   = (const float*)d_in[4];
    const float* Wx_b1  = (const float*)d_in[5];
    const float* Wh_b1  = (const float*)d_in[6];
    const float* b_b1   = (const float*)d_in[7];
    const float* Wx_f2  = (const float*)d_in[8];
    const float* Wh_f2  = (const float*)d_in[9];
    const float* b_f2   = (const float*)d_in[10];
    const float* Wx_b2  = (const float*)d_in[11];
    const float* Wh_b2  = (const float*)d_in[12];
    const float* b_b2   = (const float*)d_in[13];
    const float* hidFOH = (const float*)d_in[14];
    const float* hidFOM = (const float*)d_in[15];
    const float* hidBias= (const float*)d_in[16];
    const float* outW   = (const float*)d_in[17];
    const float* outB   = (const float*)d_in[18];
    const float* rhidFOH= (const float*)d_in[19];
    const float* rhidFOM= (const float*)d_in[20];
    const float* rhidBias=(const float*)d_in[21];
    const float* routW  = (const float*)d_in[22];
    const float* routB  = (const float*)d_in[23];

    float* ws  = (float*)d_ws;
    float* x   = ws;                  // 512*256
    float* Xf1 = x + 131072;          // 512*1024
    float* Xb1 = Xf1 + 524288;
    float* h1  = Xb1 + 524288;        // 512*512
    float* Xf2 = h1 + 262144;
    float* Xb2 = Xf2 + 524288;
    float* h2  = Xb2 + 524288;        // 512*512
    float* Hh  = h2 + 262144;
    float* Mh  = Hh + 262144;
    float* Rh  = Mh + 262144;
    float* Rm  = Rh + 262144;
    unsigned long long* stage1 = (unsigned long long*)(Rm + 262144);
    unsigned long long* stage2 = stage1 + 1024;
    _Float16* rw16 = (_Float16*)(stage2 + 1024);   // 112 x 512 f16

    float* arc_out = (float*)d_out;
    float* rel_out = arc_out + NSEQ * NSEQ;

    hipMemsetAsync(stage1, 0, 2048 * sizeof(unsigned long long), stream);
    embed_kernel<<<NSEQ, WD, 0, stream>>>(tokens, E, x);
    cvt_routw_kernel<<<512, 128, 0, stream>>>(routW, rw16);
    dim3 g1(NG / 64, NSEQ / 64);
    gemm_mfma_kernel<<<g1, 256, 0, stream>>>(x, Wx_f1, b_f1, Xf1, NSEQ, WD, NG);
    gemm_mfma_kernel<<<g1, 256, 0, stream>>>(x, Wx_b1, b_b1, Xb1, NSEQ, WD, NG);
    lstm_kernel<<<4, 512, 0, stream>>>(Xf1, Xb1, Wh_f1, Wh_b1, h1, stage1);
    gemm_mfma_kernel<<<g1, 256, 0, stream>>>(h1, Wx_f2, b_f2, Xf2, NSEQ, FEAT, NG);
    gemm_mfma_kernel<<<g1, 256, 0, stream>>>(h1, Wx_b2, b_b2, Xb2, NSEQ, FEAT, NG);
    lstm_kernel<<<4, 512, 0, stream>>>(Xf2, Xb2, Wh_f2, Wh_b2, h2, stage2);
    dim3 g2(HID / 64, NSEQ / 64);
    gemm_mfma_kernel<<<g2, 256, 0, stream>>>(h2, hidFOH, hidBias, Hh, NSEQ, FEAT, HID);
    gemm_mfma_kernel<<<g2, 256, 0, stream>>>(h2, hidFOM, nullptr, Mh, NSEQ, FEAT, HID);
    gemm_mfma_kernel<<<g2, 256, 0, stream>>>(h2, rhidFOH, rhidBias, Rh, NSEQ, FEAT, HID);
    gemm_mfma_kernel<<<g2, 256, 0, stream>>>(h2, rhidFOM, nullptr, Rm, NSEQ, FEAT, HID);
    dim3 ga(NSEQ / 16, NSEQ / 16);
    arc_kernel<<<ga, 256, 0, stream>>>(Hh, Mh, outW, outB, arc_out);
    rel_mfma_kernel<<<NSEQ * 8, 256, 0, stream>>>(Rh, Rm, rw16, routB, rel_out);
}